// Round 13
// baseline (40.666 us; speedup 1.0000x reference)
//
#include <hip/hip_runtime.h>
#include <stdint.h>

// Problem constants: IMG=512, CUT_SIZE=224, CUTN=64, B=4, C=3; sizes in [224,511]
constexpr int S   = 224;
constexpr int Wim = 512;
constexpr int Him = 512;
constexpr int PLANES = 12;                   // B*C
constexpr int N   = 64;
constexpr int SB  = 8;                       // source rows per band (R13: 16->8)
constexpr int NBANDS = Him / SB;             // 64
constexpr int NGRP = 8;                      // cutouts per block
constexpr int GROUPS = N / NGRP;             // 8
constexpr int TILES = PLANES * NBANDS;       // 768 (plane,band) tiles
constexpr int TPX   = TILES / 8;             // 96 tiles per XCD
constexpr int WPB   = 4;                     // 256 threads
constexpr int GRID  = TILES * GROUPS;        // 6144
constexpr int ROWF  = 516;                   // LDS row stride (512 + zeroed pad)

__device__ __forceinline__ void load_lds16(const float* g, float* l) {
    __builtin_amdgcn_global_load_lds(
        (const __attribute__((address_space(1))) void*)g,
        (__attribute__((address_space(3))) void*)l, 16, 0, 0);
}

// iy0 exactly as reference computes it
__device__ __forceinline__ int iy0_of(int i, float scale, int sz) {
    const float sy = fmaxf(scale * ((float)i + 0.5f) - 0.5f, 0.0f);
    return min((int)floorf(sy), sz - 1);
}

__global__ __launch_bounds__(256) void cutouts_kernel(
    const float* __restrict__ x,
    const int*   __restrict__ sizes,
    const int*   __restrict__ offx,
    const int*   __restrict__ offy,
    float*       __restrict__ out)
{
    __shared__ float lds[SB + 1][ROWF];      // 18,576 B -> 8 blocks/CU, 32 waves

    const int lane = threadIdx.x & 63;
    const int wv   = threadIdx.x >> 6;       // 0..3

    // decode: XCD-affine (plane,band) tile; consecutive locals share a tile
    const int xcd   = blockIdx.x & 7;
    const int local = blockIdx.x >> 3;       // 0..767
    const int tk    = local >> 3;            // tile-in-xcd 0..95
    const int g     = local & 7;             // cutout group 0..7
    const int t     = xcd * TPX + tk;        // 0..767
    const int pi    = t / NBANDS;            // plane 0..11
    const int b     = t - pi * NBANDS;       // band 0..63

    // zero pad cols [512..515] (hit only by weight-0 neighbor reads)
    if (threadIdx.x < (SB + 1) * 4)
        lds[threadIdx.x >> 2][Wim + (threadIdx.x & 3)] = 0.0f;

    // stage band once: 9 rows x 512 floats = 18 chunks of 1 KB DMA
    const float* plane = x + (size_t)pi * (Him * Wim);
    for (int c = wv; c < (SB + 1) * 2; c += WPB) {
        const int row  = c >> 1, half = c & 1;
        const int srow = min(SB * b + row, Him - 1);   // dup last row (wt-0 only)
        load_lds16(plane + (size_t)srow * Wim + half * 256 + lane * 4,
                   &lds[row][half * 256]);
    }

    // in-lane parallel first_ge: lane c<8 -> i_lo(cutout c); lanes 8..15 -> i_hi.
    // ONE first_ge execution per wave.
    int flv;
    {
        const int   idx = lane & 7;
        const int   nn_ = g * NGRP + idx;
        const int   szl = sizes[nn_];
        const int   oyl = offy[nn_];
        const float scl = (float)szl / (float)S;
        const int   P   = SB * b - oyl + ((lane & 8) ? SB : 0);
        int res;
        if (P <= 0) res = 0;
        else if (P > szl - 1) res = S;
        else {
            const float cc = ((float)P + 0.5f) / scl - 0.5f;
            int i = (int)ceilf(fminf(fmaxf(cc, 0.0f), (float)S));
            while (i > 0 && iy0_of(i - 1, scl, szl) >= P) --i;
            while (i < S && iy0_of(i, scl, szl) < P) ++i;
            res = i;
        }
        flv = res;
    }

    asm volatile("s_waitcnt vmcnt(0)" ::: "memory");
    __syncthreads();

    #pragma unroll 1
    for (int nn = 0; nn < NGRP; ++nn) {
        const int i_lo = __builtin_amdgcn_readlane(flv, nn);      // SGPR, uniform
        const int i_hi = __builtin_amdgcn_readlane(flv, nn + 8);
        if (i_lo >= i_hi) continue;                               // scalar branch

        const int n  = g * NGRP + nn;
        const int sz = sizes[n];
        const int oy = offy[n];
        const int ox = offx[n];
        const float scale = (float)sz / (float)S;
        const int   L     = SB * b - oy;

        // horizontal params once per (wave,cutout), reused for all its rows
        int dv[4]; float fxv[4];
        #pragma unroll
        for (int r = 0; r < 4; ++r) {
            const int   px = r * 64 + lane;
            const float sx = fmaxf(scale * ((float)px + 0.5f) - 0.5f, 0.0f);
            const float fi = floorf(sx);
            fxv[r] = sx - fi;                          // ix0 <= sz-1 (sz>=224)
            dv[r]  = ox + (int)fi;                     // d+1 <= 512: pad zeroed
        }

        float* oplane = out + (size_t)(n * PLANES + pi) * (S * S);

        for (int i = i_lo + wv; i < i_hi; i += WPB) {
            const float sy  = fmaxf(scale * ((float)i + 0.5f) - 0.5f, 0.0f);
            const float fiy = floorf(sy);
            const float fy  = sy - fiy;                // frac BEFORE clamp
            const int   rel = (int)fiy - L;            // in [0, SB-1] (partition)
            const float* l0 = &lds[rel][0];
            const float* l1 = &lds[rel + 1][0];        // rel+1 <= SB staged
            float* orow = oplane + (size_t)i * S;

            #pragma unroll
            for (int r = 0; r < 4; ++r) {
                if (r < 3 || lane < 32) {              // 224 = 3*64 + 32
                    const int   d = dv[r];
                    const float f = fxv[r];
                    const float a0 = l0[d], a1 = l0[d + 1];   // ds_read2_b32
                    const float c0 = l1[d], c1 = l1[d + 1];
                    const float top = a0 + (a1 - a0) * f;
                    const float bot = c0 + (c1 - c0) * f;
                    orow[r * 64 + lane] = top + (bot - top) * fy;
                }
            }
        }
    }
}

extern "C" void kernel_launch(void* const* d_in, const int* in_sizes, int n_in,
                              void* d_out, int out_size, void* d_ws, size_t ws_size,
                              hipStream_t stream) {
    const float* x     = (const float*)d_in[0];
    const int*   sizes = (const int*)d_in[1];
    const int*   offx  = (const int*)d_in[2];
    const int*   offy  = (const int*)d_in[3];
    float* out = (float*)d_out;

    cutouts_kernel<<<GRID, 256, 0, stream>>>(x, sizes, offx, offy, out);
}